// Round 11
// baseline (4142.307 us; speedup 1.0000x reference)
//
#include <hip/hip_runtime.h>

// ============================================================================
// SequentialVariationalIB: 2-layer LSTM (B=8,S=512,H=512) + VIB head + decoder
//
//  R11 = R10 with:
//   (a) lstm: canary data-as-flag. h0_all/h1_all memset to 0xFF per launch;
//       producers store h (agent-relaxed atomics) and DO NOT drain or flag;
//       consumers poll their own 16-float staging slice with coalesced 16B
//       agent-relaxed loads until non-canary (values land in registers).
//       2 barriers/step. No sig arrays.
//   (b) decoder GEMM single-product (sample_bf16 @ wd_bf16) — error budget
//       ~6e-3 vs 2.03e-2 threshold.
// ============================================================================

typedef __attribute__((ext_vector_type(4))) float f32x4;
typedef __attribute__((ext_vector_type(8))) short short8;
typedef __attribute__((ext_vector_type(4))) unsigned short u16x4;

#define V_SZ 32000
#define E_SZ 512
#define H_SZ 512
#define B_SZ 8
#define S_SZ 512
#define NTOK 4096            // B*S
#define G4H  2048            // 4*H

// ---------------------------------------------------------------------------
// bf16 helpers (manual RNE)
// ---------------------------------------------------------------------------
__device__ __forceinline__ unsigned short f2bf(float x) {
  unsigned int b = __float_as_uint(x);
  b += 0x7FFFu + ((b >> 16) & 1u);
  return (unsigned short)(b >> 16);
}
__device__ __forceinline__ float bf2f(unsigned short u) {
  return __uint_as_float(((unsigned int)u) << 16);
}

__device__ __forceinline__ void split4(const f32x4 v, u16x4& hv, u16x4& lv) {
  unsigned short h0 = f2bf(v.x); lv.x = f2bf(v.x - bf2f(h0)); hv.x = h0;
  unsigned short h1 = f2bf(v.y); lv.y = f2bf(v.y - bf2f(h1)); hv.y = h1;
  unsigned short h2 = f2bf(v.z); lv.z = f2bf(v.z - bf2f(h2)); hv.z = h2;
  unsigned short h3 = f2bf(v.w); lv.w = f2bf(v.w - bf2f(h3)); hv.w = h3;
}

// agent-scope cache-bypassing 16B load (2 x b64 relaxed atomic, IF-coherent)
__device__ __forceinline__ f32x4 ld16_bypass(const float* p) {
  const unsigned long long* q = (const unsigned long long*)p;
  unsigned long long a = __hip_atomic_load(&q[0], __ATOMIC_RELAXED, __HIP_MEMORY_SCOPE_AGENT);
  unsigned long long b = __hip_atomic_load(&q[1], __ATOMIC_RELAXED, __HIP_MEMORY_SCOPE_AGENT);
  f32x4 r;
  r.x = __uint_as_float((unsigned int)a);
  r.y = __uint_as_float((unsigned int)(a >> 32));
  r.z = __uint_as_float((unsigned int)b);
  r.w = __uint_as_float((unsigned int)(b >> 32));
  return r;
}
// canary check: 0xFFFFFFFF never produced by the cell (|h|<1)
__device__ __forceinline__ int chk4(const f32x4 v) {
  return (__float_as_uint(v.x) != 0xFFFFFFFFu) & (__float_as_uint(v.y) != 0xFFFFFFFFu) &
         (__float_as_uint(v.z) != 0xFFFFFFFFu) & (__float_as_uint(v.w) != 0xFFFFFFFFu);
}

// ---------------------------------------------------------------------------
// prep kernels
// ---------------------------------------------------------------------------
__global__ void split_kernel(const float* __restrict__ src,
                             unsigned short* __restrict__ hi,
                             unsigned short* __restrict__ lo, int n4) {
  int i = blockIdx.x * 256 + threadIdx.x;
  if (i >= n4) return;
  f32x4 v = ((const f32x4*)src)[i];
  u16x4 hv, lv;
  split4(v, hv, lv);
  ((u16x4*)hi)[i] = hv;
  ((u16x4*)lo)[i] = lv;
}

__global__ void cast_hi_kernel(const float* __restrict__ src,
                               unsigned short* __restrict__ hi, int n4) {
  int i = blockIdx.x * 256 + threadIdx.x;
  if (i >= n4) return;
  f32x4 v = ((const f32x4*)src)[i];
  u16x4 hv;
  hv.x = f2bf(v.x); hv.y = f2bf(v.y); hv.z = f2bf(v.z); hv.w = f2bf(v.w);
  ((u16x4*)hi)[i] = hv;
}

__global__ void bias_sum_kernel(const float* __restrict__ a0, const float* __restrict__ c0,
                                const float* __restrict__ a1, const float* __restrict__ c1,
                                float* __restrict__ o0, float* __restrict__ o1) {
  int i = blockIdx.x * 256 + threadIdx.x;
  if (i < G4H) { o0[i] = a0[i] + c0[i]; o1[i] = a1[i] + c1[i]; }
}

__global__ void embed_hi_kernel(const float* __restrict__ emb, const int* __restrict__ x,
                                unsigned short* __restrict__ hi) {
  int gid = blockIdx.x * 256 + threadIdx.x;   // NTOK * 128
  int r = gid >> 7;
  int kq = (gid & 127) << 2;
  int tok = x[r];
  f32x4 v = *(const f32x4*)(emb + (size_t)tok * E_SZ + kq);
  u16x4 hv;
  hv.x = f2bf(v.x); hv.y = f2bf(v.y); hv.z = f2bf(v.z); hv.w = f2bf(v.w);
  *(u16x4*)(hi + (size_t)r * E_SZ + kq) = hv;
}

// ---------------------------------------------------------------------------
// 2-product GEMM:  C[M,N] = Ah[M,K] @ (Bh+Bl)[N,K]^T + bias
// ---------------------------------------------------------------------------
__device__ __forceinline__ int swz32(int row, int seg) {
  return row * 32 + (((seg ^ (row & 3)) << 3));
}

__global__ __launch_bounds__(256, 2) void gemm2_kernel(
    const unsigned short* __restrict__ Ah,
    const unsigned short* __restrict__ Bh, const unsigned short* __restrict__ Bl,
    const float* __restrict__ bias, float* __restrict__ C,
    int M, int N, int K) {
  __shared__ unsigned short sA[128 * 32];
  __shared__ unsigned short sBh[128 * 32];
  __shared__ unsigned short sBl[128 * 32];

  const int t = threadIdx.x;
  const int lane = t & 63;
  const int wave = t >> 6;
  const int wr = wave >> 1, wc = wave & 1;
  const size_t m0 = (size_t)blockIdx.y * 128;
  const size_t n0 = (size_t)blockIdx.x * 128;

  f32x4 acc[4][4];
#pragma unroll
  for (int i = 0; i < 4; ++i)
#pragma unroll
    for (int j = 0; j < 4; ++j) acc[i][j] = (f32x4){0.f, 0.f, 0.f, 0.f};

  const int r0 = t >> 2;
  const int seg0 = t & 3;

  const int nk = K >> 5;
  for (int ks = 0; ks < nk; ++ks) {
    const int k0 = ks << 5;
    short8 vA[2], vBh[2], vBl[2];
#pragma unroll
    for (int r = 0; r < 2; ++r) {
      int row = r0 + r * 64;
      size_t ga = (m0 + row) * (size_t)K + k0 + seg0 * 8;
      size_t gb = (n0 + row) * (size_t)K + k0 + seg0 * 8;
      vA[r] = *(const short8*)(Ah + ga);
      vBh[r] = *(const short8*)(Bh + gb);
      vBl[r] = *(const short8*)(Bl + gb);
    }
    __syncthreads();
#pragma unroll
    for (int r = 0; r < 2; ++r) {
      int row = r0 + r * 64;
      int d = swz32(row, seg0);
      *(short8*)(sA + d) = vA[r];
      *(short8*)(sBh + d) = vBh[r];
      *(short8*)(sBl + d) = vBl[r];
    }
    __syncthreads();

    short8 a[4], bh[4], bl[4];
    const int seg = lane >> 4;
#pragma unroll
    for (int m = 0; m < 4; ++m) {
      int row = wr * 64 + m * 16 + (lane & 15);
      a[m] = *(const short8*)(sA + swz32(row, seg));
    }
#pragma unroll
    for (int n = 0; n < 4; ++n) {
      int row = wc * 64 + n * 16 + (lane & 15);
      int d = swz32(row, seg);
      bh[n] = *(const short8*)(sBh + d);
      bl[n] = *(const short8*)(sBl + d);
    }
#pragma unroll
    for (int m = 0; m < 4; ++m) {
#pragma unroll
      for (int n = 0; n < 4; ++n) {
        acc[m][n] = __builtin_amdgcn_mfma_f32_16x16x32_bf16(a[m], bh[n], acc[m][n], 0, 0, 0);
        acc[m][n] = __builtin_amdgcn_mfma_f32_16x16x32_bf16(a[m], bl[n], acc[m][n], 0, 0, 0);
      }
    }
  }

#pragma unroll
  for (int m = 0; m < 4; ++m) {
#pragma unroll
    for (int n = 0; n < 4; ++n) {
      size_t gr0 = m0 + wr * 64 + m * 16 + ((lane >> 4) << 2);
      size_t gc = n0 + wc * 64 + n * 16 + (lane & 15);
      float bv = bias ? bias[gc] : 0.f;
#pragma unroll
      for (int j = 0; j < 4; ++j) {
        C[(gr0 + j) * (size_t)N + gc] = acc[m][n][j] + bv;
      }
    }
  }
}

// ---------------------------------------------------------------------------
// 1-product GEMM (decoder):  C[M,N] = Ah[M,K] @ Bh[N,K]^T + bias
// ---------------------------------------------------------------------------
__global__ __launch_bounds__(256, 2) void gemm1_kernel(
    const unsigned short* __restrict__ Ah, const unsigned short* __restrict__ Bh,
    const float* __restrict__ bias, float* __restrict__ C,
    int M, int N, int K) {
  __shared__ unsigned short sA[128 * 32];
  __shared__ unsigned short sB[128 * 32];

  const int t = threadIdx.x;
  const int lane = t & 63;
  const int wave = t >> 6;
  const int wr = wave >> 1, wc = wave & 1;
  const size_t m0 = (size_t)blockIdx.y * 128;
  const size_t n0 = (size_t)blockIdx.x * 128;

  f32x4 acc[4][4];
#pragma unroll
  for (int i = 0; i < 4; ++i)
#pragma unroll
    for (int j = 0; j < 4; ++j) acc[i][j] = (f32x4){0.f, 0.f, 0.f, 0.f};

  const int r0 = t >> 2;
  const int seg0 = t & 3;

  const int nk = K >> 5;
  for (int ks = 0; ks < nk; ++ks) {
    const int k0 = ks << 5;
    short8 vA[2], vB[2];
#pragma unroll
    for (int r = 0; r < 2; ++r) {
      int row = r0 + r * 64;
      vA[r] = *(const short8*)(Ah + (m0 + row) * (size_t)K + k0 + seg0 * 8);
      vB[r] = *(const short8*)(Bh + (n0 + row) * (size_t)K + k0 + seg0 * 8);
    }
    __syncthreads();
#pragma unroll
    for (int r = 0; r < 2; ++r) {
      int row = r0 + r * 64;
      int d = swz32(row, seg0);
      *(short8*)(sA + d) = vA[r];
      *(short8*)(sB + d) = vB[r];
    }
    __syncthreads();

    short8 a[4], b[4];
    const int seg = lane >> 4;
#pragma unroll
    for (int m = 0; m < 4; ++m) {
      int row = wr * 64 + m * 16 + (lane & 15);
      a[m] = *(const short8*)(sA + swz32(row, seg));
    }
#pragma unroll
    for (int n = 0; n < 4; ++n) {
      int row = wc * 64 + n * 16 + (lane & 15);
      b[n] = *(const short8*)(sB + swz32(row, seg));
    }
#pragma unroll
    for (int m = 0; m < 4; ++m) {
#pragma unroll
      for (int n = 0; n < 4; ++n) {
        acc[m][n] = __builtin_amdgcn_mfma_f32_16x16x32_bf16(a[m], b[n], acc[m][n], 0, 0, 0);
      }
    }
  }

#pragma unroll
  for (int m = 0; m < 4; ++m) {
#pragma unroll
    for (int n = 0; n < 4; ++n) {
      size_t gr0 = m0 + wr * 64 + m * 16 + ((lane >> 4) << 2);
      size_t gc = n0 + wc * 64 + n * 16 + (lane & 15);
      float bv = bias ? bias[gc] : 0.f;
#pragma unroll
      for (int j = 0; j < 4; ++j) {
        C[(gr0 + j) * (size_t)N + gc] = acc[m][n][j] + bv;
      }
    }
  }
}

// ---------------------------------------------------------------------------
// persistent sequential LSTM kernel — canary data-as-flag (R11)
// 64 L0 blocks (8 units) + 128 L1 blocks (4 units), decoupled chains.
// h buffers canary-initialized to 0xFF; consumers poll their own staging
// slice with coalesced bypass loads; producers store h and move on.
// ---------------------------------------------------------------------------
#define SEQ_NB 192
#define SEQ_NB_L0 64

__device__ __forceinline__ float sigm(float x) { return 1.f / (1.f + expf(-x)); }

__global__ __launch_bounds__(256, 1) void lstm_seq_kernel(
    const float* __restrict__ gx0,    // [4096][2048] (bias folded in)
    const float* __restrict__ w_hh0,  // [2048][512]
    const float* __restrict__ w_ih1,  // [2048][512]
    const float* __restrict__ w_hh1,  // [2048][512]
    const float* __restrict__ b1s,    // [2048]
    const float* __restrict__ initst, // [2][2][512]
    float* __restrict__ h0_all,       // [512][4096]  (canary-init)
    float* __restrict__ h1_all,       // [512][4096]  (canary-init)
    unsigned short* __restrict__ hs1h) {
  const int blk = blockIdx.x;
  const int t = threadIdx.x;
  const bool isL1 = (blk >= SEQ_NB_L0);
  const int lb = isL1 ? (blk - SEQ_NB_L0) : blk;

  __shared__ float hA[8][512];
  __shared__ float hB[8][512];
  __shared__ float gates_s[32][8];

  const int tb = t >> 7;                       // batch group (4 batches)
  const int rg = isL1 ? ((t >> 5) & 3) : ((t >> 4) & 7);
  const int kg = isL1 ? (t & 31) : (t & 15);

  // ---- weights -> registers: 4 rows x 32 k-elems per thread ----
  f32x4 w[4][8];
  if (!isL1) {
#pragma unroll
    for (int rr = 0; rr < 4; ++rr) {
      int rl = rg * 4 + rr;                          // gate-row in [0,32)
      int grow = (rl >> 3) * H_SZ + lb * 8 + (rl & 7);
      const float* src = w_hh0 + (size_t)grow * H_SZ + kg * 4;
#pragma unroll
      for (int j = 0; j < 8; ++j) w[rr][j] = *(const f32x4*)(src + j * 64);
    }
  } else {
#pragma unroll
    for (int rr = 0; rr < 4; ++rr) {
      int rl = rg * 4 + rr;                          // gate-row in [0,16)
      int grow = (rl >> 2) * H_SZ + lb * 4 + (rl & 3);
      const float* s1 = w_ih1 + (size_t)grow * H_SZ + kg * 4;
      const float* s2 = w_hh1 + (size_t)grow * H_SZ + kg * 4;
#pragma unroll
      for (int j = 0; j < 4; ++j) w[rr][j] = *(const f32x4*)(s1 + j * 128);
#pragma unroll
      for (int j = 0; j < 4; ++j) w[rr][4 + j] = *(const f32x4*)(s2 + j * 128);
    }
  }

  // ---- per-lane cell state (wave 0 only) ----
  const int UPB = isL1 ? 4 : 8;
  const int nCell = UPB * 8;                       // 64 (L0) / 32 (L1)
  const int cu = t >> 3, cb = t & 7;
  const int cunit = lb * UPB + cu;
  float creg = 0.f;
  float bgi = 0.f, bgf = 0.f, bgg = 0.f, bgo = 0.f;
  if (t < nCell) {
    creg = initst[1024 + (isL1 ? 512 : 0) + cunit];
    if (isL1) {
      bgi = b1s[cunit];
      bgf = b1s[512 + cunit];
      bgg = b1s[1024 + cunit];
      bgo = b1s[1536 + cunit];
    }
  }

  for (int step = 0; step < 512; ++step) {
    // ---- prefetch gx0 gate rows for this step (cacheable) ----
    float pgi = 0.f, pgf = 0.f, pgg = 0.f, pgo = 0.f;
    if (!isL1 && t < nCell) {
      const float* gx = gx0 + ((size_t)(cb * S_SZ + step)) * G4H + cunit;
      pgi = gx[0];
      pgf = gx[512];
      pgg = gx[1024];
      pgo = gx[1536];
    }

    // ---- poll + stage (canary data-as-flag; values land in registers) ----
    // thread's slice: flat words {t, t+256, t+512, t+768} * 4  (16B each)
    float* ldA = &hA[0][0] + t * 4;
    float* ldB = &hB[0][0] + t * 4;
    if (!isL1) {
      if (step == 0) {
#pragma unroll
        for (int i = 0; i < 4; ++i) {
          int idx = t + i * 256;
          int kc = (idx & 127) << 2;
          *(f32x4*)(&hA[0][0] + idx * 4) = *(const f32x4*)(initst + kc);
        }
      } else {
        const float* s = h0_all + (size_t)(step - 1) * 4096 + (size_t)t * 4;
        f32x4 v0, v1, v2, v3;
        while (true) {
          v0 = ld16_bypass(s);
          v1 = ld16_bypass(s + 1024);
          v2 = ld16_bypass(s + 2048);
          v3 = ld16_bypass(s + 3072);
          int ok = chk4(v0) & chk4(v1) & chk4(v2) & chk4(v3);
          if (__all(ok)) break;
          __builtin_amdgcn_s_sleep(1);
        }
        *(f32x4*)ldA = v0;
        *(f32x4*)(ldA + 1024) = v1;
        *(f32x4*)(ldA + 2048) = v2;
        *(f32x4*)(ldA + 3072) = v3;
      }
    } else {
      const float* s0 = h0_all + (size_t)step * 4096 + (size_t)t * 4;
      if (step == 0) {
        f32x4 v0, v1, v2, v3;
        while (true) {
          v0 = ld16_bypass(s0);
          v1 = ld16_bypass(s0 + 1024);
          v2 = ld16_bypass(s0 + 2048);
          v3 = ld16_bypass(s0 + 3072);
          int ok = chk4(v0) & chk4(v1) & chk4(v2) & chk4(v3);
          if (__all(ok)) break;
          __builtin_amdgcn_s_sleep(1);
        }
        *(f32x4*)ldA = v0;
        *(f32x4*)(ldA + 1024) = v1;
        *(f32x4*)(ldA + 2048) = v2;
        *(f32x4*)(ldA + 3072) = v3;
#pragma unroll
        for (int i = 0; i < 4; ++i) {
          int idx = t + i * 256;
          int kc = (idx & 127) << 2;
          *(f32x4*)(&hB[0][0] + idx * 4) = *(const f32x4*)(initst + 512 + kc);
        }
      } else {
        const float* s1 = h1_all + (size_t)(step - 1) * 4096 + (size_t)t * 4;
        f32x4 a0, a1, a2, a3, b0, b1, b2, b3;
        while (true) {
          a0 = ld16_bypass(s0);
          a1 = ld16_bypass(s0 + 1024);
          a2 = ld16_bypass(s0 + 2048);
          a3 = ld16_bypass(s0 + 3072);
          b0 = ld16_bypass(s1);
          b1 = ld16_bypass(s1 + 1024);
          b2 = ld16_bypass(s1 + 2048);
          b3 = ld16_bypass(s1 + 3072);
          int ok = chk4(a0) & chk4(a1) & chk4(a2) & chk4(a3) &
                   chk4(b0) & chk4(b1) & chk4(b2) & chk4(b3);
          if (__all(ok)) break;
          __builtin_amdgcn_s_sleep(1);
        }
        *(f32x4*)ldA = a0;
        *(f32x4*)(ldA + 1024) = a1;
        *(f32x4*)(ldA + 2048) = a2;
        *(f32x4*)(ldA + 3072) = a3;
        *(f32x4*)ldB = b0;
        *(f32x4*)(ldB + 1024) = b1;
        *(f32x4*)(ldB + 2048) = b2;
        *(f32x4*)(ldB + 3072) = b3;
      }
    }
    __syncthreads();   // stage complete before matmul reads

    // ---- gate matmul: 4 rows x 4 batches per thread ----
    float acc[4][4];   // [rr][bq]
#pragma unroll
    for (int rr = 0; rr < 4; ++rr)
#pragma unroll
      for (int bq = 0; bq < 4; ++bq) acc[rr][bq] = 0.f;

    if (!isL1) {
#pragma unroll
      for (int bq = 0; bq < 4; ++bq) {
        const float* hb = &hA[tb * 4 + bq][0];
#pragma unroll
        for (int j = 0; j < 8; ++j) {
          f32x4 hq = *(const f32x4*)(hb + kg * 4 + j * 64);
#pragma unroll
          for (int rr = 0; rr < 4; ++rr)
            acc[rr][bq] += w[rr][j].x * hq.x + w[rr][j].y * hq.y +
                           w[rr][j].z * hq.z + w[rr][j].w * hq.w;
        }
      }
#pragma unroll
      for (int s = 1; s < 16; s <<= 1) {
#pragma unroll
        for (int rr = 0; rr < 4; ++rr)
#pragma unroll
          for (int bq = 0; bq < 4; ++bq)
            acc[rr][bq] += __shfl_xor(acc[rr][bq], s, 64);
      }
      if (kg == 0) {
#pragma unroll
        for (int rr = 0; rr < 4; ++rr)
#pragma unroll
          for (int bq = 0; bq < 4; ++bq)
            gates_s[rg * 4 + rr][tb * 4 + bq] = acc[rr][bq];
      }
    } else {
#pragma unroll
      for (int bq = 0; bq < 4; ++bq) {
        const int b = tb * 4 + bq;
        const float* ha = &hA[b][0];
        const float* hbp = &hB[b][0];
#pragma unroll
        for (int j = 0; j < 4; ++j) {
          f32x4 hq = *(const f32x4*)(ha + kg * 4 + j * 128);
#pragma unroll
          for (int rr = 0; rr < 4; ++rr)
            acc[rr][bq] += w[rr][j].x * hq.x + w[rr][j].y * hq.y +
                           w[rr][j].z * hq.z + w[rr][j].w * hq.w;
        }
#pragma unroll
        for (int j = 0; j < 4; ++j) {
          f32x4 hq = *(const f32x4*)(hbp + kg * 4 + j * 128);
#pragma unroll
          for (int rr = 0; rr < 4; ++rr)
            acc[rr][bq] += w[rr][4 + j].x * hq.x + w[rr][4 + j].y * hq.y +
                           w[rr][4 + j].z * hq.z + w[rr][4 + j].w * hq.w;
        }
      }
#pragma unroll
      for (int s = 1; s < 32; s <<= 1) {
#pragma unroll
        for (int rr = 0; rr < 4; ++rr)
#pragma unroll
          for (int bq = 0; bq < 4; ++bq)
            acc[rr][bq] += __shfl_xor(acc[rr][bq], s, 64);
      }
      if (kg == 0) {
#pragma unroll
        for (int rr = 0; rr < 4; ++rr)
#pragma unroll
          for (int bq = 0; bq < 4; ++bq)
            gates_s[rg * 4 + rr][tb * 4 + bq] = acc[rr][bq];
      }
    }
    __syncthreads();

    // ---- LSTM cell (wave 0): compute h, store (data IS the signal) ----
    if (t < nCell) {
      float gi, gf, gg, go;
      if (!isL1) {
        gi = gates_s[cu][cb] + pgi;
        gf = gates_s[8 + cu][cb] + pgf;
        gg = gates_s[16 + cu][cb] + pgg;
        go = gates_s[24 + cu][cb] + pgo;
      } else {
        gi = gates_s[cu][cb] + bgi;
        gf = gates_s[4 + cu][cb] + bgf;
        gg = gates_s[8 + cu][cb] + bgg;
        go = gates_s[12 + cu][cb] + bgo;
      }
      float cn = sigm(gf) * creg + sigm(gi) * tanhf(gg);
      float hval = sigm(go) * tanhf(cn);
      creg = cn;
      float* hbase = isL1 ? h1_all : h0_all;
      __hip_atomic_store(&hbase[(size_t)step * 4096 + cb * H_SZ + cunit], hval,
                         __ATOMIC_RELAXED, __HIP_MEMORY_SCOPE_AGENT);
      if (isL1) {
        // consumed post-kernel (stream order) — kernel-end flush suffices
        hs1h[(size_t)(cb * S_SZ + step) * H_SZ + cunit] = f2bf(hval);
      }
    }
    // no end-of-loop barrier: WAR on hA/hB/gates_s covered by the two
    // in-loop barriers (see R10 analysis; poll is per-thread-slice now).
  }
}

// ---------------------------------------------------------------------------
// VIB head epilogue: std=softplus, mu, sample=mu+sqrt(std)*eps
// ---------------------------------------------------------------------------
__global__ void sample_kernel(const float* __restrict__ stats, const float* __restrict__ eps,
                              unsigned short* __restrict__ sh,
                              float* __restrict__ omu, float* __restrict__ ostd) {
  int gid = blockIdx.x * 256 + threadIdx.x;  // 2097152
  int r = gid >> 9, hh = gid & 511;
  float sp = stats[(size_t)r * 1024 + hh];
  float mu = stats[(size_t)r * 1024 + 512 + hh];
  float sd = (sp > 20.f) ? sp : log1pf(expf(sp));
  float smp = mu + sqrtf(sd) * eps[gid];
  omu[gid] = mu;
  ostd[gid] = sd;
  sh[gid] = f2bf(smp);
}

// ---------------------------------------------------------------------------
extern "C" void kernel_launch(void* const* d_in, const int* in_sizes, int n_in,
                              void* d_out, int out_size, void* d_ws, size_t ws_size,
                              hipStream_t stream) {
  const float* emb    = (const float*)d_in[0];
  const float* initst = (const float*)d_in[1];
  const float* w_ih0  = (const float*)d_in[2];
  const float* w_hh0  = (const float*)d_in[3];
  const float* b_ih0  = (const float*)d_in[4];
  const float* b_hh0  = (const float*)d_in[5];
  const float* w_ih1  = (const float*)d_in[6];
  const float* w_hh1  = (const float*)d_in[7];
  const float* b_ih1  = (const float*)d_in[8];
  const float* b_hh1  = (const float*)d_in[9];
  const float* wg     = (const float*)d_in[10];
  const float* bg     = (const float*)d_in[11];
  const float* wd     = (const float*)d_in[12];
  const float* bd     = (const float*)d_in[13];
  const float* eps    = (const float*)d_in[14];
  const int*   x      = (const int*)d_in[15];

  char* ws = (char*)d_ws;
  size_t off = 0;
  auto alloc = [&](size_t sz) {
    void* p = ws + off;
    off = (off + sz + 255) & ~(size_t)255;
    return p;
  };
  float* b0s             = (float*)alloc(G4H * 4);
  float* b1s             = (float*)alloc(G4H * 4);
  unsigned short* wih0h  = (unsigned short*)alloc((size_t)G4H * E_SZ * 2);
  unsigned short* wih0l  = (unsigned short*)alloc((size_t)G4H * E_SZ * 2);
  unsigned short* wgh    = (unsigned short*)alloc((size_t)1024 * H_SZ * 2);
  unsigned short* wgl    = (unsigned short*)alloc((size_t)1024 * H_SZ * 2);
  unsigned short* wdh    = (unsigned short*)alloc((size_t)V_SZ * H_SZ * 2);
  unsigned short* a0h    = (unsigned short*)alloc((size_t)NTOK * E_SZ * 2);
  float* gx0             = (float*)alloc((size_t)NTOK * G4H * 4);
  float* h0_all          = (float*)alloc((size_t)512 * 4096 * 4);
  float* h1_all          = (float*)alloc((size_t)512 * 4096 * 4);
  unsigned short* hs1h   = (unsigned short*)alloc((size_t)NTOK * H_SZ * 2);
  float* stats           = (float*)alloc((size_t)NTOK * 1024 * 4);
  unsigned short* smph   = (unsigned short*)alloc((size_t)NTOK * H_SZ * 2);

  float* out_logits = (float*)d_out;                       // [4096][32000]
  float* out_mu     = out_logits + (size_t)NTOK * V_SZ;    // [4096][512]
  float* out_std    = out_mu + (size_t)NTOK * H_SZ;

  // canary-init h buffers (graph replays reuse ws): 0xFFFFFFFF per word
  (void)hipMemsetAsync(h0_all, 0xFF, (size_t)512 * 4096 * 4, stream);
  (void)hipMemsetAsync(h1_all, 0xFF, (size_t)512 * 4096 * 4, stream);

  // 1. weight preps
  split_kernel<<<(G4H * E_SZ / 4 + 255) / 256, 256, 0, stream>>>(w_ih0, wih0h, wih0l, G4H * E_SZ / 4);
  split_kernel<<<(1024 * H_SZ / 4 + 255) / 256, 256, 0, stream>>>(wg, wgh, wgl, 1024 * H_SZ / 4);
  cast_hi_kernel<<<(V_SZ * H_SZ / 4 + 255) / 256, 256, 0, stream>>>(wd, wdh, V_SZ * H_SZ / 4);
  bias_sum_kernel<<<8, 256, 0, stream>>>(b_ih0, b_hh0, b_ih1, b_hh1, b0s, b1s);

  // 2. embedding gather (hi plane)
  embed_hi_kernel<<<NTOK * 128 / 256, 256, 0, stream>>>(emb, x, a0h);

  // 3. gx0 = emb @ w_ih0^T + b0s
  gemm2_kernel<<<dim3(G4H / 128, NTOK / 128), 256, 0, stream>>>(
      a0h, wih0h, wih0l, b0s, gx0, NTOK, G4H, E_SZ);

  // 4. sequential LSTM (canary data-as-flag)
  lstm_seq_kernel<<<SEQ_NB, 256, 0, stream>>>(
      gx0, w_hh0, w_ih1, w_hh1, b1s, initst, h0_all, h1_all, hs1h);

  // 5. stats = hs1 @ wg^T + bg
  gemm2_kernel<<<dim3(1024 / 128, NTOK / 128), 256, 0, stream>>>(
      hs1h, wgh, wgl, bg, stats, NTOK, 1024, H_SZ);

  // 6. VIB head
  sample_kernel<<<NTOK * H_SZ / 256, 256, 0, stream>>>(stats, eps, smph, out_mu, out_std);

  // 7. logits = sample @ wd^T + bd  (single-product)
  gemm1_kernel<<<dim3(V_SZ / 128, NTOK / 128), 256, 0, stream>>>(
      smph, wdh, bd, out_logits, NTOK, V_SZ, H_SZ);
}

// Round 15
// 3439.955 us; speedup vs baseline: 1.2042x; 1.2042x over previous
//
#include <hip/hip_runtime.h>

// ============================================================================
// SequentialVariationalIB: 2-layer LSTM (B=8,S=512,H=512) + VIB head + decoder
//
//  R15 = best-proven combination (no new mechanisms):
//   - lstm: exact R10 kernel (R6 signaling structure; 64 L0 + 128 L1 blocks,
//     per-producer flag slots, plain coalesced staging of virgin lines,
//     4-row register-reuse matmul; hs1 stored after the flag). 3.21 ms.
//   - GEMMs: gx0/stats 2-product (Ah @ (Bh+Bl)); decoder 1-product
//     (sample_bf16 @ wd_bf16) — R11-proven at absmax 3.9e-3.
// ============================================================================

typedef __attribute__((ext_vector_type(4))) float f32x4;
typedef __attribute__((ext_vector_type(8))) short short8;
typedef __attribute__((ext_vector_type(4))) unsigned short u16x4;

#define V_SZ 32000
#define E_SZ 512
#define H_SZ 512
#define B_SZ 8
#define S_SZ 512
#define NTOK 4096            // B*S
#define G4H  2048            // 4*H

// ---------------------------------------------------------------------------
// bf16 helpers (manual RNE)
// ---------------------------------------------------------------------------
__device__ __forceinline__ unsigned short f2bf(float x) {
  unsigned int b = __float_as_uint(x);
  b += 0x7FFFu + ((b >> 16) & 1u);
  return (unsigned short)(b >> 16);
}
__device__ __forceinline__ float bf2f(unsigned short u) {
  return __uint_as_float(((unsigned int)u) << 16);
}

__device__ __forceinline__ void split4(const f32x4 v, u16x4& hv, u16x4& lv) {
  unsigned short h0 = f2bf(v.x); lv.x = f2bf(v.x - bf2f(h0)); hv.x = h0;
  unsigned short h1 = f2bf(v.y); lv.y = f2bf(v.y - bf2f(h1)); hv.y = h1;
  unsigned short h2 = f2bf(v.z); lv.z = f2bf(v.z - bf2f(h2)); hv.z = h2;
  unsigned short h3 = f2bf(v.w); lv.w = f2bf(v.w - bf2f(h3)); hv.w = h3;
}

// ---------------------------------------------------------------------------
// prep kernels
// ---------------------------------------------------------------------------
__global__ void split_kernel(const float* __restrict__ src,
                             unsigned short* __restrict__ hi,
                             unsigned short* __restrict__ lo, int n4) {
  int i = blockIdx.x * 256 + threadIdx.x;
  if (i >= n4) return;
  f32x4 v = ((const f32x4*)src)[i];
  u16x4 hv, lv;
  split4(v, hv, lv);
  ((u16x4*)hi)[i] = hv;
  ((u16x4*)lo)[i] = lv;
}

__global__ void cast_hi_kernel(const float* __restrict__ src,
                               unsigned short* __restrict__ hi, int n4) {
  int i = blockIdx.x * 256 + threadIdx.x;
  if (i >= n4) return;
  f32x4 v = ((const f32x4*)src)[i];
  u16x4 hv;
  hv.x = f2bf(v.x); hv.y = f2bf(v.y); hv.z = f2bf(v.z); hv.w = f2bf(v.w);
  ((u16x4*)hi)[i] = hv;
}

__global__ void bias_sum_kernel(const float* __restrict__ a0, const float* __restrict__ c0,
                                const float* __restrict__ a1, const float* __restrict__ c1,
                                float* __restrict__ o0, float* __restrict__ o1) {
  int i = blockIdx.x * 256 + threadIdx.x;
  if (i < G4H) { o0[i] = a0[i] + c0[i]; o1[i] = a1[i] + c1[i]; }
}

// embedding gather -> bf16 hi plane
__global__ void embed_hi_kernel(const float* __restrict__ emb, const int* __restrict__ x,
                                unsigned short* __restrict__ hi) {
  int gid = blockIdx.x * 256 + threadIdx.x;   // NTOK * 128
  int r = gid >> 7;
  int kq = (gid & 127) << 2;
  int tok = x[r];
  f32x4 v = *(const f32x4*)(emb + (size_t)tok * E_SZ + kq);
  u16x4 hv;
  hv.x = f2bf(v.x); hv.y = f2bf(v.y); hv.z = f2bf(v.z); hv.w = f2bf(v.w);
  *(u16x4*)(hi + (size_t)r * E_SZ + kq) = hv;
}

// ---------------------------------------------------------------------------
// 2-product GEMM:  C[M,N] = Ah[M,K] @ (Bh+Bl)[N,K]^T + bias
// ---------------------------------------------------------------------------
__device__ __forceinline__ int swz32(int row, int seg) {
  return row * 32 + (((seg ^ (row & 3)) << 3));
}

__global__ __launch_bounds__(256, 2) void gemm2_kernel(
    const unsigned short* __restrict__ Ah,
    const unsigned short* __restrict__ Bh, const unsigned short* __restrict__ Bl,
    const float* __restrict__ bias, float* __restrict__ C,
    int M, int N, int K) {
  __shared__ unsigned short sA[128 * 32];
  __shared__ unsigned short sBh[128 * 32];
  __shared__ unsigned short sBl[128 * 32];

  const int t = threadIdx.x;
  const int lane = t & 63;
  const int wave = t >> 6;
  const int wr = wave >> 1, wc = wave & 1;
  const size_t m0 = (size_t)blockIdx.y * 128;
  const size_t n0 = (size_t)blockIdx.x * 128;

  f32x4 acc[4][4];
#pragma unroll
  for (int i = 0; i < 4; ++i)
#pragma unroll
    for (int j = 0; j < 4; ++j) acc[i][j] = (f32x4){0.f, 0.f, 0.f, 0.f};

  const int r0 = t >> 2;
  const int seg0 = t & 3;

  const int nk = K >> 5;
  for (int ks = 0; ks < nk; ++ks) {
    const int k0 = ks << 5;
    short8 vA[2], vBh[2], vBl[2];
#pragma unroll
    for (int r = 0; r < 2; ++r) {
      int row = r0 + r * 64;
      size_t ga = (m0 + row) * (size_t)K + k0 + seg0 * 8;
      size_t gb = (n0 + row) * (size_t)K + k0 + seg0 * 8;
      vA[r] = *(const short8*)(Ah + ga);
      vBh[r] = *(const short8*)(Bh + gb);
      vBl[r] = *(const short8*)(Bl + gb);
    }
    __syncthreads();
#pragma unroll
    for (int r = 0; r < 2; ++r) {
      int row = r0 + r * 64;
      int d = swz32(row, seg0);
      *(short8*)(sA + d) = vA[r];
      *(short8*)(sBh + d) = vBh[r];
      *(short8*)(sBl + d) = vBl[r];
    }
    __syncthreads();

    short8 a[4], bh[4], bl[4];
    const int seg = lane >> 4;
#pragma unroll
    for (int m = 0; m < 4; ++m) {
      int row = wr * 64 + m * 16 + (lane & 15);
      a[m] = *(const short8*)(sA + swz32(row, seg));
    }
#pragma unroll
    for (int n = 0; n < 4; ++n) {
      int row = wc * 64 + n * 16 + (lane & 15);
      int d = swz32(row, seg);
      bh[n] = *(const short8*)(sBh + d);
      bl[n] = *(const short8*)(sBl + d);
    }
#pragma unroll
    for (int m = 0; m < 4; ++m) {
#pragma unroll
      for (int n = 0; n < 4; ++n) {
        acc[m][n] = __builtin_amdgcn_mfma_f32_16x16x32_bf16(a[m], bh[n], acc[m][n], 0, 0, 0);
        acc[m][n] = __builtin_amdgcn_mfma_f32_16x16x32_bf16(a[m], bl[n], acc[m][n], 0, 0, 0);
      }
    }
  }

#pragma unroll
  for (int m = 0; m < 4; ++m) {
#pragma unroll
    for (int n = 0; n < 4; ++n) {
      size_t gr0 = m0 + wr * 64 + m * 16 + ((lane >> 4) << 2);
      size_t gc = n0 + wc * 64 + n * 16 + (lane & 15);
      float bv = bias ? bias[gc] : 0.f;
#pragma unroll
      for (int j = 0; j < 4; ++j) {
        C[(gr0 + j) * (size_t)N + gc] = acc[m][n][j] + bv;
      }
    }
  }
}

// ---------------------------------------------------------------------------
// 1-product GEMM (decoder):  C[M,N] = Ah[M,K] @ Bh[N,K]^T + bias
// ---------------------------------------------------------------------------
__global__ __launch_bounds__(256, 2) void gemm1_kernel(
    const unsigned short* __restrict__ Ah, const unsigned short* __restrict__ Bh,
    const float* __restrict__ bias, float* __restrict__ C,
    int M, int N, int K) {
  __shared__ unsigned short sA[128 * 32];
  __shared__ unsigned short sB[128 * 32];

  const int t = threadIdx.x;
  const int lane = t & 63;
  const int wave = t >> 6;
  const int wr = wave >> 1, wc = wave & 1;
  const size_t m0 = (size_t)blockIdx.y * 128;
  const size_t n0 = (size_t)blockIdx.x * 128;

  f32x4 acc[4][4];
#pragma unroll
  for (int i = 0; i < 4; ++i)
#pragma unroll
    for (int j = 0; j < 4; ++j) acc[i][j] = (f32x4){0.f, 0.f, 0.f, 0.f};

  const int r0 = t >> 2;
  const int seg0 = t & 3;

  const int nk = K >> 5;
  for (int ks = 0; ks < nk; ++ks) {
    const int k0 = ks << 5;
    short8 vA[2], vB[2];
#pragma unroll
    for (int r = 0; r < 2; ++r) {
      int row = r0 + r * 64;
      vA[r] = *(const short8*)(Ah + (m0 + row) * (size_t)K + k0 + seg0 * 8);
      vB[r] = *(const short8*)(Bh + (n0 + row) * (size_t)K + k0 + seg0 * 8);
    }
    __syncthreads();
#pragma unroll
    for (int r = 0; r < 2; ++r) {
      int row = r0 + r * 64;
      int d = swz32(row, seg0);
      *(short8*)(sA + d) = vA[r];
      *(short8*)(sB + d) = vB[r];
    }
    __syncthreads();

    short8 a[4], b[4];
    const int seg = lane >> 4;
#pragma unroll
    for (int m = 0; m < 4; ++m) {
      int row = wr * 64 + m * 16 + (lane & 15);
      a[m] = *(const short8*)(sA + swz32(row, seg));
    }
#pragma unroll
    for (int n = 0; n < 4; ++n) {
      int row = wc * 64 + n * 16 + (lane & 15);
      b[n] = *(const short8*)(sB + swz32(row, seg));
    }
#pragma unroll
    for (int m = 0; m < 4; ++m) {
#pragma unroll
      for (int n = 0; n < 4; ++n) {
        acc[m][n] = __builtin_amdgcn_mfma_f32_16x16x32_bf16(a[m], b[n], acc[m][n], 0, 0, 0);
      }
    }
  }

#pragma unroll
  for (int m = 0; m < 4; ++m) {
#pragma unroll
    for (int n = 0; n < 4; ++n) {
      size_t gr0 = m0 + wr * 64 + m * 16 + ((lane >> 4) << 2);
      size_t gc = n0 + wc * 64 + n * 16 + (lane & 15);
      float bv = bias ? bias[gc] : 0.f;
#pragma unroll
      for (int j = 0; j < 4; ++j) {
        C[(gr0 + j) * (size_t)N + gc] = acc[m][n][j] + bv;
      }
    }
  }
}

// ---------------------------------------------------------------------------
// persistent sequential LSTM kernel — EXACT R10 (best measured: 3.21 ms).
// 64 L0 blocks (8 units) + 128 L1 blocks (4 units), decoupled chains,
// per-producer flag slots, plain coalesced staging of virgin lines,
// 4-row register-reuse matmul mapping; hs1 stored after the flag.
// ---------------------------------------------------------------------------
#define SEQ_NB 192
#define SEQ_NB_L0 64

__device__ __forceinline__ float sigm(float x) { return 1.f / (1.f + expf(-x)); }

__global__ __launch_bounds__(256, 1) void lstm_seq_kernel(
    const float* __restrict__ gx0,    // [4096][2048] (bias folded in)
    const float* __restrict__ w_hh0,  // [2048][512]
    const float* __restrict__ w_ih1,  // [2048][512]
    const float* __restrict__ w_hh1,  // [2048][512]
    const float* __restrict__ b1s,    // [2048]
    const float* __restrict__ initst, // [2][2][512]
    float* __restrict__ h0_all,       // [512][8][512]
    float* __restrict__ h1_all,       // [512][8][512]
    unsigned short* __restrict__ hs1h,// [4096][512]
    unsigned int* __restrict__ sig0,  // [512][64]
    unsigned int* __restrict__ sig1) {// [512][128]
  const int blk = blockIdx.x;
  const int t = threadIdx.x;
  const bool isL1 = (blk >= SEQ_NB_L0);
  const int lb = isL1 ? (blk - SEQ_NB_L0) : blk;

  __shared__ float hA[8][512];
  __shared__ float hB[8][512];
  __shared__ float gates_s[32][8];

  const int tb = t >> 7;                       // batch group (4 batches)
  const int rg = isL1 ? ((t >> 5) & 3) : ((t >> 4) & 7);
  const int kg = isL1 ? (t & 31) : (t & 15);

  // ---- weights -> registers: 4 rows x 32 k-elems per thread ----
  f32x4 w[4][8];
  if (!isL1) {
#pragma unroll
    for (int rr = 0; rr < 4; ++rr) {
      int rl = rg * 4 + rr;                          // gate-row in [0,32)
      int grow = (rl >> 3) * H_SZ + lb * 8 + (rl & 7);
      const float* src = w_hh0 + (size_t)grow * H_SZ + kg * 4;
#pragma unroll
      for (int j = 0; j < 8; ++j) w[rr][j] = *(const f32x4*)(src + j * 64);
    }
  } else {
#pragma unroll
    for (int rr = 0; rr < 4; ++rr) {
      int rl = rg * 4 + rr;                          // gate-row in [0,16)
      int grow = (rl >> 2) * H_SZ + lb * 4 + (rl & 3);
      const float* s1 = w_ih1 + (size_t)grow * H_SZ + kg * 4;
      const float* s2 = w_hh1 + (size_t)grow * H_SZ + kg * 4;
#pragma unroll
      for (int j = 0; j < 4; ++j) w[rr][j] = *(const f32x4*)(s1 + j * 128);
#pragma unroll
      for (int j = 0; j < 4; ++j) w[rr][4 + j] = *(const f32x4*)(s2 + j * 128);
    }
  }

  // ---- per-lane cell state (wave 0 only) ----
  const int UPB = isL1 ? 4 : 8;
  const int nCell = UPB * 8;                       // 64 (L0) / 32 (L1)
  const int cu = t >> 3, cb = t & 7;
  const int cunit = lb * UPB + cu;
  float creg = 0.f;
  float bgi = 0.f, bgf = 0.f, bgg = 0.f, bgo = 0.f;
  if (t < nCell) {
    creg = initst[1024 + (isL1 ? 512 : 0) + cunit];
    if (isL1) {
      bgi = b1s[cunit];
      bgf = b1s[512 + cunit];
      bgg = b1s[1024 + cunit];
      bgo = b1s[1536 + cunit];
    }
  }

  for (int step = 0; step < 512; ++step) {
    // ---- prefetch gx0 gate rows for this step (cacheable) ----
    float pgi = 0.f, pgf = 0.f, pgg = 0.f, pgo = 0.f;
    if (!isL1 && t < nCell) {
      const float* gx = gx0 + ((size_t)(cb * S_SZ + step)) * G4H + cunit;
      pgi = gx[0];
      pgf = gx[512];
      pgg = gx[1024];
      pgo = gx[1536];
    }

    // ---- wait for inputs (wave 0, relaxed agent loads) ----
    if (t < 64) {
      if (!isL1) {
        if (step > 0) {
          const unsigned int* s0 = sig0 + (size_t)(step - 1) * 64;
          while (true) {
            unsigned int v = __hip_atomic_load(&s0[t], __ATOMIC_RELAXED, __HIP_MEMORY_SCOPE_AGENT);
            if (__all(v != 0)) break;
            __builtin_amdgcn_s_sleep(1);
          }
        }
      } else {
        const unsigned int* s0 = sig0 + (size_t)step * 64;
        const unsigned int* s1 = (step > 0) ? (sig1 + (size_t)(step - 1) * 128) : nullptr;
        while (true) {
          int ok = (__hip_atomic_load(&s0[t], __ATOMIC_RELAXED, __HIP_MEMORY_SCOPE_AGENT) != 0);
          if (s1) {
            ok &= (__hip_atomic_load(&s1[t], __ATOMIC_RELAXED, __HIP_MEMORY_SCOPE_AGENT) != 0);
            ok &= (__hip_atomic_load(&s1[64 + t], __ATOMIC_RELAXED, __HIP_MEMORY_SCOPE_AGENT) != 0);
          }
          if (__all(ok)) break;
          __builtin_amdgcn_s_sleep(1);
        }
      }
    }
    __syncthreads();   // orders staging loads after poll exit

    // ---- stage h into LDS via plain coalesced loads (virgin lines) ----
    if (!isL1) {
      if (step == 0) {
#pragma unroll
        for (int i = 0; i < 4; ++i) {
          int idx = t + i * 256;
          int b = idx >> 7;
          int kc = (idx & 127) << 2;
          *(f32x4*)&hA[b][kc] = *(const f32x4*)(initst + kc);
        }
      } else {
        const float* src = h0_all + (size_t)(step - 1) * 4096;
#pragma unroll
        for (int i = 0; i < 4; ++i) {
          int idx = t + i * 256;
          int b = idx >> 7;
          int kc = (idx & 127) << 2;
          *(f32x4*)&hA[b][kc] = *(const f32x4*)(src + b * H_SZ + kc);
        }
      }
    } else {
      const float* s0 = h0_all + (size_t)step * 4096;
      const float* s1 = (step == 0) ? nullptr : (h1_all + (size_t)(step - 1) * 4096);
#pragma unroll
      for (int i = 0; i < 4; ++i) {
        int idx = t + i * 256;
        int b = idx >> 7;
        int kc = (idx & 127) << 2;
        *(f32x4*)&hA[b][kc] = *(const f32x4*)(s0 + b * H_SZ + kc);
        f32x4 v1 = s1 ? *(const f32x4*)(s1 + b * H_SZ + kc)
                      : *(const f32x4*)(initst + 512 + kc);
        *(f32x4*)&hB[b][kc] = v1;
      }
    }
    __syncthreads();

    // ---- gate matmul: 4 rows x 4 batches per thread ----
    float acc[4][4];   // [rr][bq]
#pragma unroll
    for (int rr = 0; rr < 4; ++rr)
#pragma unroll
      for (int bq = 0; bq < 4; ++bq) acc[rr][bq] = 0.f;

    if (!isL1) {
#pragma unroll
      for (int bq = 0; bq < 4; ++bq) {
        const float* hb = &hA[tb * 4 + bq][0];
#pragma unroll
        for (int j = 0; j < 8; ++j) {
          f32x4 hq = *(const f32x4*)(hb + kg * 4 + j * 64);
#pragma unroll
          for (int rr = 0; rr < 4; ++rr)
            acc[rr][bq] += w[rr][j].x * hq.x + w[rr][j].y * hq.y +
                           w[rr][j].z * hq.z + w[rr][j].w * hq.w;
        }
      }
#pragma unroll
      for (int s = 1; s < 16; s <<= 1) {
#pragma unroll
        for (int rr = 0; rr < 4; ++rr)
#pragma unroll
          for (int bq = 0; bq < 4; ++bq)
            acc[rr][bq] += __shfl_xor(acc[rr][bq], s, 64);
      }
      if (kg == 0) {
#pragma unroll
        for (int rr = 0; rr < 4; ++rr)
#pragma unroll
          for (int bq = 0; bq < 4; ++bq)
            gates_s[rg * 4 + rr][tb * 4 + bq] = acc[rr][bq];
      }
    } else {
#pragma unroll
      for (int bq = 0; bq < 4; ++bq) {
        const int b = tb * 4 + bq;
        const float* ha = &hA[b][0];
        const float* hbp = &hB[b][0];
#pragma unroll
        for (int j = 0; j < 4; ++j) {
          f32x4 hq = *(const f32x4*)(ha + kg * 4 + j * 128);
#pragma unroll
          for (int rr = 0; rr < 4; ++rr)
            acc[rr][bq] += w[rr][j].x * hq.x + w[rr][j].y * hq.y +
                           w[rr][j].z * hq.z + w[rr][j].w * hq.w;
        }
#pragma unroll
        for (int j = 0; j < 4; ++j) {
          f32x4 hq = *(const f32x4*)(hbp + kg * 4 + j * 128);
#pragma unroll
          for (int rr = 0; rr < 4; ++rr)
            acc[rr][bq] += w[rr][4 + j].x * hq.x + w[rr][4 + j].y * hq.y +
                           w[rr][4 + j].z * hq.z + w[rr][4 + j].w * hq.w;
        }
      }
#pragma unroll
      for (int s = 1; s < 32; s <<= 1) {
#pragma unroll
        for (int rr = 0; rr < 4; ++rr)
#pragma unroll
          for (int bq = 0; bq < 4; ++bq)
            acc[rr][bq] += __shfl_xor(acc[rr][bq], s, 64);
      }
      if (kg == 0) {
#pragma unroll
        for (int rr = 0; rr < 4; ++rr)
#pragma unroll
          for (int bq = 0; bq < 4; ++bq)
            gates_s[rg * 4 + rr][tb * 4 + bq] = acc[rr][bq];
      }
    }
    __syncthreads();

    // ---- LSTM cell (wave 0) + signal ----
    float hval = 0.f;
    if (t < nCell) {
      float gi, gf, gg, go;
      if (!isL1) {
        gi = gates_s[cu][cb] + pgi;
        gf = gates_s[8 + cu][cb] + pgf;
        gg = gates_s[16 + cu][cb] + pgg;
        go = gates_s[24 + cu][cb] + pgo;
      } else {
        gi = gates_s[cu][cb] + bgi;
        gf = gates_s[4 + cu][cb] + bgf;
        gg = gates_s[8 + cu][cb] + bgg;
        go = gates_s[12 + cu][cb] + bgo;
      }
      float cn = sigm(gf) * creg + sigm(gi) * tanhf(gg);
      hval = sigm(go) * tanhf(cn);
      creg = cn;
      if (!isL1) {
        __hip_atomic_store(&h0_all[(size_t)step * 4096 + cb * H_SZ + cunit], hval,
                           __ATOMIC_RELAXED, __HIP_MEMORY_SCOPE_AGENT);
      } else {
        __hip_atomic_store(&h1_all[(size_t)step * 4096 + cb * H_SZ + cunit], hval,
                           __ATOMIC_RELAXED, __HIP_MEMORY_SCOPE_AGENT);
      }
    }
    if (t == 0) {
      // producing wave == signaling wave: vmcnt(0) orders the h stores
      // (coherence-point ops) before the flag store; no cache maintenance.
      asm volatile("s_waitcnt vmcnt(0)" ::: "memory");
      unsigned int* slot = isL1 ? (sig1 + (size_t)step * 128 + lb)
                                : (sig0 + (size_t)step * 64 + lb);
      __hip_atomic_store(slot, 1u, __ATOMIC_RELAXED, __HIP_MEMORY_SCOPE_AGENT);
    }
    // hs1 bf16 plane: consumed only after kernel end (stream order), so it
    // goes AFTER the flag — off the critical vmcnt drain.
    if (isL1 && t < nCell) {
      hs1h[(size_t)(cb * S_SZ + step) * H_SZ + cunit] = f2bf(hval);
    }
    // no end-of-loop barrier: WAR hazards covered by next iter's post-stage sync
  }
}

// ---------------------------------------------------------------------------
// VIB head epilogue: std=softplus, mu, sample=mu+sqrt(std)*eps
// ---------------------------------------------------------------------------
__global__ void sample_kernel(const float* __restrict__ stats, const float* __restrict__ eps,
                              unsigned short* __restrict__ sh,
                              float* __restrict__ omu, float* __restrict__ ostd) {
  int gid = blockIdx.x * 256 + threadIdx.x;  // 2097152
  int r = gid >> 9, hh = gid & 511;
  float sp = stats[(size_t)r * 1024 + hh];
  float mu = stats[(size_t)r * 1024 + 512 + hh];
  float sd = (sp > 20.f) ? sp : log1pf(expf(sp));
  float smp = mu + sqrtf(sd) * eps[gid];
  omu[gid] = mu;
  ostd[gid] = sd;
  sh[gid] = f2bf(smp);
}

// ---------------------------------------------------------------------------
extern "C" void kernel_launch(void* const* d_in, const int* in_sizes, int n_in,
                              void* d_out, int out_size, void* d_ws, size_t ws_size,
                              hipStream_t stream) {
  const float* emb    = (const float*)d_in[0];
  const float* initst = (const float*)d_in[1];
  const float* w_ih0  = (const float*)d_in[2];
  const float* w_hh0  = (const float*)d_in[3];
  const float* b_ih0  = (const float*)d_in[4];
  const float* b_hh0  = (const float*)d_in[5];
  const float* w_ih1  = (const float*)d_in[6];
  const float* w_hh1  = (const float*)d_in[7];
  const float* b_ih1  = (const float*)d_in[8];
  const float* b_hh1  = (const float*)d_in[9];
  const float* wg     = (const float*)d_in[10];
  const float* bg     = (const float*)d_in[11];
  const float* wd     = (const float*)d_in[12];
  const float* bd     = (const float*)d_in[13];
  const float* eps    = (const float*)d_in[14];
  const int*   x      = (const int*)d_in[15];

  char* ws = (char*)d_ws;
  size_t off = 0;
  auto alloc = [&](size_t sz) {
    void* p = ws + off;
    off = (off + sz + 255) & ~(size_t)255;
    return p;
  };
  unsigned int* sig0     = (unsigned int*)alloc((size_t)512 * 64 * 4);
  unsigned int* sig1     = (unsigned int*)alloc((size_t)512 * 128 * 4);
  float* b0s             = (float*)alloc(G4H * 4);
  float* b1s             = (float*)alloc(G4H * 4);
  unsigned short* wih0h  = (unsigned short*)alloc((size_t)G4H * E_SZ * 2);
  unsigned short* wih0l  = (unsigned short*)alloc((size_t)G4H * E_SZ * 2);
  unsigned short* wgh    = (unsigned short*)alloc((size_t)1024 * H_SZ * 2);
  unsigned short* wgl    = (unsigned short*)alloc((size_t)1024 * H_SZ * 2);
  unsigned short* wdh    = (unsigned short*)alloc((size_t)V_SZ * H_SZ * 2);
  unsigned short* a0h    = (unsigned short*)alloc((size_t)NTOK * E_SZ * 2);
  float* gx0             = (float*)alloc((size_t)NTOK * G4H * 4);
  float* h0_all          = (float*)alloc((size_t)512 * 4096 * 4);
  float* h1_all          = (float*)alloc((size_t)512 * 4096 * 4);
  unsigned short* hs1h   = (unsigned short*)alloc((size_t)NTOK * H_SZ * 2);
  float* stats           = (float*)alloc((size_t)NTOK * 1024 * 4);
  unsigned short* smph   = (unsigned short*)alloc((size_t)NTOK * H_SZ * 2);

  float* out_logits = (float*)d_out;                       // [4096][32000]
  float* out_mu     = out_logits + (size_t)NTOK * V_SZ;    // [4096][512]
  float* out_std    = out_mu + (size_t)NTOK * H_SZ;

  // reset flag slots (graph replays reuse ws)
  (void)hipMemsetAsync(sig0, 0, (size_t)512 * 64 * 4, stream);
  (void)hipMemsetAsync(sig1, 0, (size_t)512 * 128 * 4, stream);

  // 1. weight preps (gx0/stats B operands keep hi+lo; decoder hi only)
  split_kernel<<<(G4H * E_SZ / 4 + 255) / 256, 256, 0, stream>>>(w_ih0, wih0h, wih0l, G4H * E_SZ / 4);
  split_kernel<<<(1024 * H_SZ / 4 + 255) / 256, 256, 0, stream>>>(wg, wgh, wgl, 1024 * H_SZ / 4);
  cast_hi_kernel<<<(V_SZ * H_SZ / 4 + 255) / 256, 256, 0, stream>>>(wd, wdh, V_SZ * H_SZ / 4);
  bias_sum_kernel<<<8, 256, 0, stream>>>(b_ih0, b_hh0, b_ih1, b_hh1, b0s, b1s);

  // 2. embedding gather (hi plane)
  embed_hi_kernel<<<NTOK * 128 / 256, 256, 0, stream>>>(emb, x, a0h);

  // 3. gx0 = emb @ w_ih0^T + b0s
  gemm2_kernel<<<dim3(G4H / 128, NTOK / 128), 256, 0, stream>>>(
      a0h, wih0h, wih0l, b0s, gx0, NTOK, G4H, E_SZ);

  // 4. sequential LSTM (R10 structure)
  lstm_seq_kernel<<<SEQ_NB, 256, 0, stream>>>(
      gx0, w_hh0, w_ih1, w_hh1, b1s, initst, h0_all, h1_all, hs1h, sig0, sig1);

  // 5. stats = hs1 @ wg^T + bg
  gemm2_kernel<<<dim3(1024 / 128, NTOK / 128), 256, 0, stream>>>(
      hs1h, wgh, wgl, bg, stats, NTOK, 1024, H_SZ);

  // 6. VIB head
  sample_kernel<<<NTOK * H_SZ / 256, 256, 0, stream>>>(stats, eps, smph, out_mu, out_std);

  // 7. logits = sample @ wd^T + bd  (1-product; R11-proven at 3.9e-3)
  gemm1_kernel<<<dim3(V_SZ / 128, NTOK / 128), 256, 0, stream>>>(
      smph, wdh, bd, out_logits, NTOK, V_SZ, H_SZ);
}